// Round 1
// baseline (640.167 us; speedup 1.0000x reference)
//
#include <hip/hip_runtime.h>

#define N_NODES 100000
#define N_EDGES 600000

__device__ __forceinline__ float elu_f(float v) {
    return v > 0.0f ? v : (__expf(v) - 1.0f);
}

// Detect whether edge_index arrived as int64 (odd 32-bit words all zero) or int32.
extern "C" __global__ void k_detect(const unsigned* __restrict__ ei, int* __restrict__ flag) {
    int t = threadIdx.x;  // 64 threads
    unsigned v = ei[2 * t + 1];
    unsigned long long b = __ballot(v == 0u);
    if (t == 0) *flag = (b == ~0ull) ? 1 : 0;
}

// P[n][0:128] = x[n] @ W1[0:128,:], P[n][128:256] = x[n] @ W1[128:256,:]
// grid = n_node_tiles * 2 (half = blockIdx.x & 1), 256 threads.
extern "C" __global__ __launch_bounds__(256, 1)
void k1_node_linear(const float* __restrict__ x, const float* __restrict__ W1,
                    float* __restrict__ P) {
    __shared__ float sW[128 * 128];    // sW[k*128+j] = W1[(half*128+k)*128+j]
    __shared__ float sXT[128 * 128];   // [k][node_local]
    const int t = threadIdx.x;
    const int half = blockIdx.x & 1;
    const int tile = blockIdx.x >> 1;
    const int n0 = tile * 128;

    const float* Wsrc = W1 + half * (128 * 128);
#pragma unroll
    for (int r = 0; r < 16; ++r) {
        int idx = (r * 256 + t) * 4;
        *(float4*)(&sW[idx]) = *(const float4*)(Wsrc + idx);
    }
#pragma unroll 4
    for (int r = 0; r < 16; ++r) {
        int ch = r * 256 + t;
        int nl = ch & 127;        // consecutive lanes -> consecutive nl (conflict-free LDS writes)
        int kc = ch >> 7;         // 0..31
        int n = n0 + nl;
        float4 v = make_float4(0.f, 0.f, 0.f, 0.f);
        if (n < N_NODES) v = *(const float4*)(x + (size_t)n * 128 + kc * 4);
        int k0 = kc * 4;
        sXT[(k0 + 0) * 128 + nl] = v.x;
        sXT[(k0 + 1) * 128 + nl] = v.y;
        sXT[(k0 + 2) * 128 + nl] = v.z;
        sXT[(k0 + 3) * 128 + nl] = v.w;
    }
    __syncthreads();

    const int gn = t >> 4;   // 0..15 node-group
    const int gc = t & 15;   // 0..15 col-group
    const int nl0 = gn * 8;
    const int c0 = gc * 8;

    float acc[8][8];
#pragma unroll
    for (int i = 0; i < 8; ++i)
#pragma unroll
        for (int j = 0; j < 8; ++j) acc[i][j] = 0.f;

#pragma unroll 2
    for (int k = 0; k < 128; ++k) {
        float4 ha = *(const float4*)(&sXT[k * 128 + nl0]);
        float4 hb = *(const float4*)(&sXT[k * 128 + nl0 + 4]);
        float4 wa = *(const float4*)(&sW[k * 128 + c0]);
        float4 wb = *(const float4*)(&sW[k * 128 + c0 + 4]);
        float hv[8] = {ha.x, ha.y, ha.z, ha.w, hb.x, hb.y, hb.z, hb.w};
        float wv[8] = {wa.x, wa.y, wa.z, wa.w, wb.x, wb.y, wb.z, wb.w};
#pragma unroll
        for (int i = 0; i < 8; ++i)
#pragma unroll
            for (int j = 0; j < 8; ++j) acc[i][j] += hv[i] * wv[j];
    }

    const int cbase = half * 128 + c0;
#pragma unroll
    for (int i = 0; i < 8; ++i) {
        int n = n0 + nl0 + i;
        if (n < N_NODES) {
            float4 v0 = make_float4(acc[i][0], acc[i][1], acc[i][2], acc[i][3]);
            float4 v1 = make_float4(acc[i][4], acc[i][5], acc[i][6], acc[i][7]);
            *(float4*)(P + (size_t)n * 256 + cbase) = v0;
            *(float4*)(P + (size_t)n * 256 + cbase + 4) = v1;
        }
    }
}

// Per 128-edge tile: h1 = elu(A[src]+B[tgt]+b1); h2 = elu(h1@W2+b2); out = h2@W3+b3
extern "C" __global__ __launch_bounds__(256, 1)
void k2_edge_mlp(const float* __restrict__ P, const void* __restrict__ eiv,
                 const float* __restrict__ b1, const float* __restrict__ W2,
                 const float* __restrict__ b2, const float* __restrict__ W3,
                 const float* __restrict__ b3, const int* __restrict__ flag,
                 float* __restrict__ out, int n_tiles) {
    __shared__ float sW2[128 * 128];   // 64 KB
    __shared__ float sH[128 * 128];    // 64 KB, h1 transposed: [k][edge_local]
    __shared__ float sW3[128];
    __shared__ float sB2[128];
    __shared__ float sB1[128];
    __shared__ int sSrc[128];
    __shared__ int sTgt[128];

    const int t = threadIdx.x;
    const int mode64 = *flag;
    const float b3v = b3[0];

#pragma unroll
    for (int r = 0; r < 16; ++r) {
        int idx = (r * 256 + t) * 4;
        *(float4*)(&sW2[idx]) = *(const float4*)(W2 + idx);
    }
    if (t < 128) { sW3[t] = W3[t]; sB2[t] = b2[t]; sB1[t] = b1[t]; }

    const int ge = t >> 4, gc = t & 15;
    const int el0 = ge * 8, c0 = gc * 8;

    for (int tile = blockIdx.x; tile < n_tiles; tile += gridDim.x) {
        const int e0 = tile * 128;
        __syncthreads();  // also covers initial sW2/sB* loads; protects sSrc/sH reuse
        if (t < 128) {
            int e = e0 + t;
            int s = 0, g = 0;
            if (e < N_EDGES) {
                if (mode64) {
                    s = (int)((const long long*)eiv)[e];
                    g = (int)((const long long*)eiv)[N_EDGES + e];
                } else {
                    s = ((const int*)eiv)[e];
                    g = ((const int*)eiv)[N_EDGES + e];
                }
            }
            sSrc[t] = s;
            sTgt[t] = g;
        }
        __syncthreads();

#pragma unroll 4
        for (int r = 0; r < 16; ++r) {
            int ch = r * 256 + t;
            int le = ch & 127;
            int kc = ch >> 7;
            int k0 = kc * 4;
            int s = sSrc[le], g = sTgt[le];
            float4 a = *(const float4*)(P + (size_t)s * 256 + k0);
            float4 bb = *(const float4*)(P + (size_t)g * 256 + 128 + k0);
            sH[(k0 + 0) * 128 + le] = elu_f(a.x + bb.x + sB1[k0 + 0]);
            sH[(k0 + 1) * 128 + le] = elu_f(a.y + bb.y + sB1[k0 + 1]);
            sH[(k0 + 2) * 128 + le] = elu_f(a.z + bb.z + sB1[k0 + 2]);
            sH[(k0 + 3) * 128 + le] = elu_f(a.w + bb.w + sB1[k0 + 3]);
        }
        __syncthreads();

        float acc[8][8];
#pragma unroll
        for (int i = 0; i < 8; ++i)
#pragma unroll
            for (int j = 0; j < 8; ++j) acc[i][j] = 0.f;

#pragma unroll 2
        for (int k = 0; k < 128; ++k) {
            float4 ha = *(const float4*)(&sH[k * 128 + el0]);
            float4 hb = *(const float4*)(&sH[k * 128 + el0 + 4]);
            float4 wa = *(const float4*)(&sW2[k * 128 + c0]);
            float4 wb = *(const float4*)(&sW2[k * 128 + c0 + 4]);
            float hv[8] = {ha.x, ha.y, ha.z, ha.w, hb.x, hb.y, hb.z, hb.w};
            float wv[8] = {wa.x, wa.y, wa.z, wa.w, wb.x, wb.y, wb.z, wb.w};
#pragma unroll
            for (int i = 0; i < 8; ++i)
#pragma unroll
                for (int j = 0; j < 8; ++j) acc[i][j] += hv[i] * wv[j];
        }

        float pout[8];
#pragma unroll
        for (int i = 0; i < 8; ++i) pout[i] = 0.f;
#pragma unroll
        for (int j = 0; j < 8; ++j) {
            float w3 = sW3[c0 + j];
            float bb2 = sB2[c0 + j];
#pragma unroll
            for (int i = 0; i < 8; ++i) {
                pout[i] += elu_f(acc[i][j] + bb2) * w3;
            }
        }
        // reduce across the 16 col-groups (contiguous 16-lane segments)
#pragma unroll
        for (int m = 1; m < 16; m <<= 1) {
#pragma unroll
            for (int i = 0; i < 8; ++i) pout[i] += __shfl_xor(pout[i], m, 64);
        }
        if (gc == 0) {
#pragma unroll
            for (int i = 0; i < 8; ++i) {
                int e = e0 + el0 + i;
                if (e < N_EDGES) out[e] = pout[i] + b3v;
            }
        }
    }
}

extern "C" void kernel_launch(void* const* d_in, const int* in_sizes, int n_in,
                              void* d_out, int out_size, void* d_ws, size_t ws_size,
                              hipStream_t stream) {
    const float* x  = (const float*)d_in[0];
    const void*  ei = d_in[1];
    const float* W1 = (const float*)d_in[2];
    const float* b1 = (const float*)d_in[3];
    const float* W2 = (const float*)d_in[4];
    const float* b2 = (const float*)d_in[5];
    const float* W3 = (const float*)d_in[6];
    const float* b3 = (const float*)d_in[7];
    float* out = (float*)d_out;

    int* flag = (int*)d_ws;
    float* P = (float*)((char*)d_ws + 256);  // 100000 * 256 floats = 102.4 MB

    k_detect<<<1, 64, 0, stream>>>((const unsigned*)ei, flag);

    int n_node_tiles = (N_NODES + 127) / 128;  // 782
    k1_node_linear<<<n_node_tiles * 2, 256, 0, stream>>>(x, W1, P);

    int n_tiles = (N_EDGES + 127) / 128;       // 4688
    k2_edge_mlp<<<1024, 256, 0, stream>>>(P, ei, b1, W2, b2, W3, b3, flag, out, n_tiles);
}

// Round 2
// 263.395 us; speedup vs baseline: 2.4304x; 2.4304x over previous
//
#include <hip/hip_runtime.h>

#define N_NODES 100000
#define N_EDGES 600000
#define NT1 782    // node tiles of 128
#define NT2 4688   // edge tiles of 128
#define LDH 136    // padded row stride (bf16 elems): 272B = 17*16B -> 2-way bank conflicts only

typedef __attribute__((ext_vector_type(8))) short bf16x8;
typedef __attribute__((ext_vector_type(4))) float f32x4;

__device__ __forceinline__ float elu_f(float v) {
    return v > 0.0f ? v : (__expf(v) - 1.0f);
}

__device__ __forceinline__ unsigned short bf_hi(float f) {
    unsigned u = __float_as_uint(f);
    return (unsigned short)((u + 0x7fffu + ((u >> 16) & 1u)) >> 16);
}

__device__ __forceinline__ void split2(float f, unsigned short& h, unsigned short& l) {
    h = bf_hi(f);
    float fh = __uint_as_float(((unsigned)h) << 16);
    l = bf_hi(f - fh);
}

// Detect whether edge_index arrived as int64 (odd 32-bit words all zero) or int32.
extern "C" __global__ void k_detect(const unsigned* __restrict__ ei, int* __restrict__ flag) {
    int t = threadIdx.x;  // 64 threads
    unsigned v = ei[2 * t + 1];
    unsigned long long b = __ballot(v == 0u);
    if (t == 0) *flag = (b == ~0ull) ? 1 : 0;
}

// P[n][0:128] = x[n] @ W1[0:128,:];  P[n][128:256] = x[n] @ W1[128:256,:]
// Persistent: blocks [0,256) do half 0, [256,512) do half 1. Split-bf16 MFMA (3 passes).
extern "C" __global__ __launch_bounds__(256, 2)
void k1_node_linear(const float* __restrict__ x, const float* __restrict__ W1,
                    float* __restrict__ P) {
    __shared__ __align__(16) unsigned short sXhi[128 * LDH];
    __shared__ __align__(16) unsigned short sXlo[128 * LDH];

    const int t = threadIdx.x;
    const int w = t >> 6, lane = t & 63;
    const int ln = lane & 15, kg = lane >> 4;
    const int half = blockIdx.x >> 8;
    const int t0 = blockIdx.x & 255;

    // W1 fragments for this wave's 32-col strip, cached in registers across all tiles.
    bf16x8 bhi[2][4], blo[2][4];
#pragma unroll
    for (int ctl = 0; ctl < 2; ++ctl) {
        const int n = w * 32 + ctl * 16 + ln;
#pragma unroll
        for (int ks = 0; ks < 4; ++ks) {
            bf16x8 vh, vl;
#pragma unroll
            for (int j = 0; j < 8; ++j) {
                int k = half * 128 + ks * 32 + kg * 8 + j;
                unsigned short h, l;
                split2(W1[k * 128 + n], h, l);
                vh[j] = (short)h; vl[j] = (short)l;
            }
            bhi[ctl][ks] = vh; blo[ctl][ks] = vl;
        }
    }

    for (int tile = t0; tile < NT1; tile += 256) {
        const int n0 = tile * 128;
        __syncthreads();
        // Stage x tile, split into hi/lo bf16.
#pragma unroll 2
        for (int r = 0; r < 8; ++r) {
            int ch = r * 256 + t;
            int le = ch >> 4, kc = ch & 15;
            int n = n0 + le;
            float4 a0 = make_float4(0.f, 0.f, 0.f, 0.f), a1 = a0;
            if (n < N_NODES) {
                const float* p = x + (size_t)n * 128 + kc * 8;
                a0 = *(const float4*)p; a1 = *(const float4*)(p + 4);
            }
            float f[8] = {a0.x, a0.y, a0.z, a0.w, a1.x, a1.y, a1.z, a1.w};
            bf16x8 vh, vl;
#pragma unroll
            for (int j = 0; j < 8; ++j) {
                unsigned short h, l; split2(f[j], h, l);
                vh[j] = (short)h; vl[j] = (short)l;
            }
            int idx = le * LDH + kc * 8;
            *(bf16x8*)(&sXhi[idx]) = vh;
            *(bf16x8*)(&sXlo[idx]) = vl;
        }
        __syncthreads();

        f32x4 acc[8][2];
#pragma unroll
        for (int rt = 0; rt < 8; ++rt)
#pragma unroll
            for (int c = 0; c < 2; ++c) acc[rt][c] = (f32x4){0.f, 0.f, 0.f, 0.f};

#pragma unroll
        for (int ks = 0; ks < 4; ++ks) {
#pragma unroll
            for (int rt = 0; rt < 8; ++rt) {
                int aidx = (rt * 16 + ln) * LDH + ks * 32 + kg * 8;
                bf16x8 ah = *(const bf16x8*)(&sXhi[aidx]);
                bf16x8 al = *(const bf16x8*)(&sXlo[aidx]);
#pragma unroll
                for (int c = 0; c < 2; ++c) {
                    acc[rt][c] = __builtin_amdgcn_mfma_f32_16x16x32_bf16(ah, bhi[c][ks], acc[rt][c], 0, 0, 0);
                    acc[rt][c] = __builtin_amdgcn_mfma_f32_16x16x32_bf16(ah, blo[c][ks], acc[rt][c], 0, 0, 0);
                    acc[rt][c] = __builtin_amdgcn_mfma_f32_16x16x32_bf16(al, bhi[c][ks], acc[rt][c], 0, 0, 0);
                }
            }
        }

        // Store: C/D layout col=lane&15, row=(lane>>4)*4+reg  [measured m89/m91]
#pragma unroll
        for (int rt = 0; rt < 8; ++rt)
#pragma unroll
            for (int c = 0; c < 2; ++c) {
                int col = half * 128 + w * 32 + c * 16 + ln;
#pragma unroll
                for (int reg = 0; reg < 4; ++reg) {
                    int n = n0 + rt * 16 + kg * 4 + reg;
                    if (n < N_NODES) P[(size_t)n * 256 + col] = acc[rt][c][reg];
                }
            }
    }
}

// Per 128-edge tile: h1=elu(A[src]+B[tgt]+b1); h2=elu(h1@W2+b2); out=h2@W3+b3.
// Layer-2 via split-bf16 MFMA, W2 fragments in registers, layer-3 fused.
extern "C" __global__ __launch_bounds__(256, 2)
void k2_edge_mlp(const float* __restrict__ P, const void* __restrict__ eiv,
                 const float* __restrict__ b1, const float* __restrict__ W2,
                 const float* __restrict__ b2, const float* __restrict__ W3,
                 const float* __restrict__ b3, const int* __restrict__ flag,
                 float* __restrict__ out) {
    __shared__ __align__(16) unsigned short sHhi[128 * LDH];
    __shared__ __align__(16) unsigned short sHlo[128 * LDH];
    __shared__ float sPart[4 * 128];
    __shared__ float sB1[128], sB2[128], sW3[128];
    __shared__ int sSrc[128], sTgt[128];

    const int t = threadIdx.x;
    const int w = t >> 6, lane = t & 63;
    const int ln = lane & 15, kg = lane >> 4;
    const int mode64 = *flag;
    const float b3v = b3[0];

    if (t < 128) { sB1[t] = b1[t]; sB2[t] = b2[t]; sW3[t] = W3[t]; }

    // W2 fragments for this wave's 32-col strip (registers, loaded once).
    bf16x8 bhi[2][4], blo[2][4];
#pragma unroll
    for (int c = 0; c < 2; ++c) {
        const int n = w * 32 + c * 16 + ln;
#pragma unroll
        for (int ks = 0; ks < 4; ++ks) {
            bf16x8 vh, vl;
#pragma unroll
            for (int j = 0; j < 8; ++j) {
                int k = ks * 32 + kg * 8 + j;
                unsigned short h, l;
                split2(W2[k * 128 + n], h, l);
                vh[j] = (short)h; vl[j] = (short)l;
            }
            bhi[c][ks] = vh; blo[c][ks] = vl;
        }
    }

    for (int tile = blockIdx.x; tile < NT2; tile += gridDim.x) {
        const int e0 = tile * 128;
        __syncthreads();  // protect sSrc/sH/sPart from previous iteration
        if (t < 128) {
            int e = e0 + t;
            int s = 0, g = 0;
            if (e < N_EDGES) {
                if (mode64) {
                    s = (int)((const long long*)eiv)[e];
                    g = (int)((const long long*)eiv)[N_EDGES + e];
                } else {
                    s = ((const int*)eiv)[e];
                    g = ((const int*)eiv)[N_EDGES + e];
                }
            }
            sSrc[t] = s; sTgt[t] = g;
        }
        __syncthreads();

        // Gather + bias + elu + split into hi/lo bf16.
#pragma unroll 2
        for (int r = 0; r < 8; ++r) {
            int ch = r * 256 + t;
            int le = ch >> 4, kc = ch & 15;
            int s = sSrc[le], g = sTgt[le];
            const float* pa = P + (size_t)s * 256 + kc * 8;
            const float* pb = P + (size_t)g * 256 + 128 + kc * 8;
            float4 a0 = *(const float4*)pa, a1 = *(const float4*)(pa + 4);
            float4 c0 = *(const float4*)pb, c1 = *(const float4*)(pb + 4);
            float fa[8] = {a0.x, a0.y, a0.z, a0.w, a1.x, a1.y, a1.z, a1.w};
            float fb[8] = {c0.x, c0.y, c0.z, c0.w, c1.x, c1.y, c1.z, c1.w};
            bf16x8 vh, vl;
#pragma unroll
            for (int j = 0; j < 8; ++j) {
                float hv = elu_f(fa[j] + fb[j] + sB1[kc * 8 + j]);
                unsigned short h, l; split2(hv, h, l);
                vh[j] = (short)h; vl[j] = (short)l;
            }
            int idx = le * LDH + kc * 8;
            *(bf16x8*)(&sHhi[idx]) = vh;
            *(bf16x8*)(&sHlo[idx]) = vl;
        }
        __syncthreads();

        f32x4 acc[8][2];
#pragma unroll
        for (int rt = 0; rt < 8; ++rt)
#pragma unroll
            for (int c = 0; c < 2; ++c) acc[rt][c] = (f32x4){0.f, 0.f, 0.f, 0.f};

#pragma unroll
        for (int ks = 0; ks < 4; ++ks) {
#pragma unroll
            for (int rt = 0; rt < 8; ++rt) {
                int aidx = (rt * 16 + ln) * LDH + ks * 32 + kg * 8;
                bf16x8 ah = *(const bf16x8*)(&sHhi[aidx]);
                bf16x8 al = *(const bf16x8*)(&sHlo[aidx]);
#pragma unroll
                for (int c = 0; c < 2; ++c) {
                    acc[rt][c] = __builtin_amdgcn_mfma_f32_16x16x32_bf16(ah, bhi[c][ks], acc[rt][c], 0, 0, 0);
                    acc[rt][c] = __builtin_amdgcn_mfma_f32_16x16x32_bf16(ah, blo[c][ks], acc[rt][c], 0, 0, 0);
                    acc[rt][c] = __builtin_amdgcn_mfma_f32_16x16x32_bf16(al, bhi[c][ks], acc[rt][c], 0, 0, 0);
                }
            }
        }

        // Layer 3 fused: per-lane partial dot over its 2 cols, 16-lane shuffle reduce.
#pragma unroll
        for (int rt = 0; rt < 8; ++rt) {
            float p[4] = {0.f, 0.f, 0.f, 0.f};
#pragma unroll
            for (int c = 0; c < 2; ++c) {
                int col = w * 32 + c * 16 + ln;
                float w3v = sW3[col], b2v = sB2[col];
#pragma unroll
                for (int reg = 0; reg < 4; ++reg)
                    p[reg] += elu_f(acc[rt][c][reg] + b2v) * w3v;
            }
#pragma unroll
            for (int m = 1; m < 16; m <<= 1)
#pragma unroll
                for (int reg = 0; reg < 4; ++reg) p[reg] += __shfl_xor(p[reg], m, 64);
            if (ln == 0) {
#pragma unroll
                for (int reg = 0; reg < 4; ++reg)
                    sPart[w * 128 + rt * 16 + kg * 4 + reg] = p[reg];
            }
        }
        __syncthreads();
        if (t < 128) {
            int e = e0 + t;
            if (e < N_EDGES)
                out[e] = sPart[t] + sPart[128 + t] + sPart[256 + t] + sPart[384 + t] + b3v;
        }
    }
}

extern "C" void kernel_launch(void* const* d_in, const int* in_sizes, int n_in,
                              void* d_out, int out_size, void* d_ws, size_t ws_size,
                              hipStream_t stream) {
    const float* x  = (const float*)d_in[0];
    const void*  ei = d_in[1];
    const float* W1 = (const float*)d_in[2];
    const float* b1 = (const float*)d_in[3];
    const float* W2 = (const float*)d_in[4];
    const float* b2 = (const float*)d_in[5];
    const float* W3 = (const float*)d_in[6];
    const float* b3 = (const float*)d_in[7];
    float* out = (float*)d_out;

    int* flag = (int*)d_ws;
    float* P = (float*)((char*)d_ws + 256);  // 100000 * 256 floats = 102.4 MB

    k_detect<<<1, 64, 0, stream>>>((const unsigned*)ei, flag);
    k1_node_linear<<<512, 256, 0, stream>>>(x, W1, P);
    k2_edge_mlp<<<512, 256, 0, stream>>>(P, ei, b1, W2, b2, W3, b3, flag, out);
}

// Round 3
// 254.308 us; speedup vs baseline: 2.5173x; 1.0357x over previous
//
#include <hip/hip_runtime.h>

#define N_NODES 100000
#define N_EDGES 600000
#define NT1 782    // node tiles of 128
#define NT2 4688   // edge tiles of 128
#define LDH 136    // padded row stride (bf16 elems), 16B-aligned rows
#define G1H 384    // k1 blocks per half (grid = 768)

typedef __attribute__((ext_vector_type(8))) short bf16x8;
typedef __attribute__((ext_vector_type(4))) float f32x4;

__device__ __forceinline__ float elu_f(float v) {
    return v > 0.0f ? v : (__expf(v) - 1.0f);
}

__device__ __forceinline__ unsigned short bf_rne(float f) {
    unsigned u = __float_as_uint(f);
    return (unsigned short)((u + 0x7fffu + ((u >> 16) & 1u)) >> 16);
}

__device__ __forceinline__ void split2(float f, unsigned short& h, unsigned short& l) {
    h = bf_rne(f);
    float fh = __uint_as_float(((unsigned)h) << 16);
    l = bf_rne(f - fh);
}

// Detect whether edge_index arrived as int64 (odd 32-bit words all zero) or int32.
extern "C" __global__ void k_detect(const unsigned* __restrict__ ei, int* __restrict__ flag) {
    int t = threadIdx.x;  // 64 threads
    unsigned v = ei[2 * t + 1];
    unsigned long long b = __ballot(v == 0u);
    if (t == 0) *flag = (b == ~0ull) ? 1 : 0;
}

// P[n][half*128 + j] = x[n] @ W1[half*128 + k][j] over k.
// 2-pass split-bf16: A = RNE(x) single bf16; B = W1 split hi+lo (exact to 2^-17).
extern "C" __global__ __launch_bounds__(256, 3)
void k1_node_linear(const float* __restrict__ x, const float* __restrict__ W1,
                    float* __restrict__ P) {
    __shared__ __align__(16) unsigned short sX[128 * LDH];

    const int t = threadIdx.x;
    const int w = t >> 6, lane = t & 63;
    const int ln = lane & 15, kg = lane >> 4;
    const int kcf = t & 15;   // fixed k-chunk per thread for staging
    const int lef = t >> 4;   // row-group base for staging
    const int half = (blockIdx.x >= G1H) ? 1 : 0;
    const int t0 = blockIdx.x - half * G1H;

    // W1 fragments (hi+lo) for this wave's 32-col strip, cached in registers.
    bf16x8 bhi[2][4], blo[2][4];
#pragma unroll
    for (int c = 0; c < 2; ++c) {
        const int n = w * 32 + c * 16 + ln;
#pragma unroll
        for (int ks = 0; ks < 4; ++ks) {
            bf16x8 vh, vl;
#pragma unroll
            for (int j = 0; j < 8; ++j) {
                int k = half * 128 + ks * 32 + kg * 8 + j;
                unsigned short h, l;
                split2(W1[k * 128 + n], h, l);
                vh[j] = (short)h; vl[j] = (short)l;
            }
            bhi[c][ks] = vh; blo[c][ks] = vl;
        }
    }

    for (int tile = t0; tile < NT1; tile += G1H) {
        const int n0 = tile * 128;
        __syncthreads();
#pragma unroll 2
        for (int r = 0; r < 8; ++r) {
            int le = r * 16 + lef;
            int n = n0 + le;
            float4 a0 = make_float4(0.f, 0.f, 0.f, 0.f), a1 = a0;
            if (n < N_NODES) {
                const float* p = x + (size_t)n * 128 + kcf * 8;
                a0 = *(const float4*)p; a1 = *(const float4*)(p + 4);
            }
            float f[8] = {a0.x, a0.y, a0.z, a0.w, a1.x, a1.y, a1.z, a1.w};
            bf16x8 vh;
#pragma unroll
            for (int j = 0; j < 8; ++j) vh[j] = (short)bf_rne(f[j]);
            *(bf16x8*)(&sX[le * LDH + kcf * 8]) = vh;
        }
        __syncthreads();

        f32x4 acc[8][2];
#pragma unroll
        for (int rt = 0; rt < 8; ++rt)
#pragma unroll
            for (int c = 0; c < 2; ++c) acc[rt][c] = (f32x4){0.f, 0.f, 0.f, 0.f};

#pragma unroll
        for (int ks = 0; ks < 4; ++ks) {
#pragma unroll
            for (int rt = 0; rt < 8; ++rt) {
                bf16x8 a = *(const bf16x8*)(&sX[(rt * 16 + ln) * LDH + ks * 32 + kg * 8]);
#pragma unroll
                for (int c = 0; c < 2; ++c) {
                    acc[rt][c] = __builtin_amdgcn_mfma_f32_16x16x32_bf16(a, bhi[c][ks], acc[rt][c], 0, 0, 0);
                    acc[rt][c] = __builtin_amdgcn_mfma_f32_16x16x32_bf16(a, blo[c][ks], acc[rt][c], 0, 0, 0);
                }
            }
        }

        // C/D layout: col=lane&15, row=(lane>>4)*4+reg  [measured m89/m91]
#pragma unroll
        for (int rt = 0; rt < 8; ++rt)
#pragma unroll
            for (int c = 0; c < 2; ++c) {
                int col = half * 128 + w * 32 + c * 16 + ln;
#pragma unroll
                for (int reg = 0; reg < 4; ++reg) {
                    int n = n0 + rt * 16 + kg * 4 + reg;
                    if (n < N_NODES) P[(size_t)n * 256 + col] = acc[rt][c][reg];
                }
            }
    }
}

// Per 128-edge tile: h1=elu(A[src]+B[tgt]+b1); h2=elu(h1@W2+b2); out=h2@W3+b3.
// 2-pass: A = RNE(h1) single bf16 in LDS; B = W2 split hi+lo in registers.
extern "C" __global__ __launch_bounds__(256, 3)
void k2_edge_mlp(const float* __restrict__ P, const void* __restrict__ eiv,
                 const float* __restrict__ b1, const float* __restrict__ W2,
                 const float* __restrict__ b2, const float* __restrict__ W3,
                 const float* __restrict__ b3, const int* __restrict__ flag,
                 float* __restrict__ out) {
    __shared__ __align__(16) unsigned short sH[128 * LDH];
    __shared__ float sPart[4 * 128];
    __shared__ int sSrc[128], sTgt[128];

    const int t = threadIdx.x;
    const int w = t >> 6, lane = t & 63;
    const int ln = lane & 15, kg = lane >> 4;
    const int kcf = t & 15;
    const int lef = t >> 4;
    const int mode64 = *flag;
    const float b3v = b3[0];

    // Loop-invariant register caches.
    float b1v[8];
#pragma unroll
    for (int j = 0; j < 8; ++j) b1v[j] = b1[kcf * 8 + j];
    float w3v[2], b2v[2];
#pragma unroll
    for (int c = 0; c < 2; ++c) {
        int col = w * 32 + c * 16 + ln;
        w3v[c] = W3[col]; b2v[c] = b2[col];
    }

    // W2 fragments (hi+lo) for this wave's 32-col strip.
    bf16x8 bhi[2][4], blo[2][4];
#pragma unroll
    for (int c = 0; c < 2; ++c) {
        const int n = w * 32 + c * 16 + ln;
#pragma unroll
        for (int ks = 0; ks < 4; ++ks) {
            bf16x8 vh, vl;
#pragma unroll
            for (int j = 0; j < 8; ++j) {
                int k = ks * 32 + kg * 8 + j;
                unsigned short h, l;
                split2(W2[k * 128 + n], h, l);
                vh[j] = (short)h; vl[j] = (short)l;
            }
            bhi[c][ks] = vh; blo[c][ks] = vl;
        }
    }

    for (int tile = blockIdx.x; tile < NT2; tile += gridDim.x) {
        const int e0 = tile * 128;
        __syncthreads();  // protect sSrc/sH/sPart from previous iteration
        if (t < 128) {
            int e = e0 + t;
            int s = 0, g = 0;
            if (e < N_EDGES) {
                if (mode64) {
                    s = (int)((const long long*)eiv)[e];
                    g = (int)((const long long*)eiv)[N_EDGES + e];
                } else {
                    s = ((const int*)eiv)[e];
                    g = ((const int*)eiv)[N_EDGES + e];
                }
            }
            sSrc[t] = s; sTgt[t] = g;
        }
        __syncthreads();

        // Gather + bias + elu + RNE bf16.
#pragma unroll 2
        for (int r = 0; r < 8; ++r) {
            int le = r * 16 + lef;
            int s = sSrc[le], g = sTgt[le];
            const float* pa = P + (size_t)s * 256 + kcf * 8;
            const float* pb = P + (size_t)g * 256 + 128 + kcf * 8;
            float4 a0 = *(const float4*)pa, a1 = *(const float4*)(pa + 4);
            float4 c0 = *(const float4*)pb, c1 = *(const float4*)(pb + 4);
            float fa[8] = {a0.x, a0.y, a0.z, a0.w, a1.x, a1.y, a1.z, a1.w};
            float fb[8] = {c0.x, c0.y, c0.z, c0.w, c1.x, c1.y, c1.z, c1.w};
            bf16x8 vh;
#pragma unroll
            for (int j = 0; j < 8; ++j)
                vh[j] = (short)bf_rne(elu_f(fa[j] + fb[j] + b1v[j]));
            *(bf16x8*)(&sH[le * LDH + kcf * 8]) = vh;
        }
        __syncthreads();

        f32x4 acc[8][2];
#pragma unroll
        for (int rt = 0; rt < 8; ++rt)
#pragma unroll
            for (int c = 0; c < 2; ++c) acc[rt][c] = (f32x4){0.f, 0.f, 0.f, 0.f};

#pragma unroll
        for (int ks = 0; ks < 4; ++ks) {
#pragma unroll
            for (int rt = 0; rt < 8; ++rt) {
                bf16x8 a = *(const bf16x8*)(&sH[(rt * 16 + ln) * LDH + ks * 32 + kg * 8]);
#pragma unroll
                for (int c = 0; c < 2; ++c) {
                    acc[rt][c] = __builtin_amdgcn_mfma_f32_16x16x32_bf16(a, bhi[c][ks], acc[rt][c], 0, 0, 0);
                    acc[rt][c] = __builtin_amdgcn_mfma_f32_16x16x32_bf16(a, blo[c][ks], acc[rt][c], 0, 0, 0);
                }
            }
        }

        // Layer 3 fused: per-lane partial dot over its 2 cols, 16-lane shuffle reduce.
#pragma unroll
        for (int rt = 0; rt < 8; ++rt) {
            float p[4] = {0.f, 0.f, 0.f, 0.f};
#pragma unroll
            for (int c = 0; c < 2; ++c) {
#pragma unroll
                for (int reg = 0; reg < 4; ++reg)
                    p[reg] += elu_f(acc[rt][c][reg] + b2v[c]) * w3v[c];
            }
#pragma unroll
            for (int m = 1; m < 16; m <<= 1)
#pragma unroll
                for (int reg = 0; reg < 4; ++reg) p[reg] += __shfl_xor(p[reg], m, 64);
            if (ln == 0) {
#pragma unroll
                for (int reg = 0; reg < 4; ++reg)
                    sPart[w * 128 + rt * 16 + kg * 4 + reg] = p[reg];
            }
        }
        __syncthreads();
        if (t < 128) {
            int e = e0 + t;
            if (e < N_EDGES)
                out[e] = sPart[t] + sPart[128 + t] + sPart[256 + t] + sPart[384 + t] + b3v;
        }
    }
}

extern "C" void kernel_launch(void* const* d_in, const int* in_sizes, int n_in,
                              void* d_out, int out_size, void* d_ws, size_t ws_size,
                              hipStream_t stream) {
    const float* x  = (const float*)d_in[0];
    const void*  ei = d_in[1];
    const float* W1 = (const float*)d_in[2];
    const float* b1 = (const float*)d_in[3];
    const float* W2 = (const float*)d_in[4];
    const float* b2 = (const float*)d_in[5];
    const float* W3 = (const float*)d_in[6];
    const float* b3 = (const float*)d_in[7];
    float* out = (float*)d_out;

    int* flag = (int*)d_ws;
    float* P = (float*)((char*)d_ws + 256);  // 100000 * 256 floats = 102.4 MB

    k_detect<<<1, 64, 0, stream>>>((const unsigned*)ei, flag);
    k1_node_linear<<<768, 256, 0, stream>>>(x, W1, P);
    k2_edge_mlp<<<768, 256, 0, stream>>>(P, ei, b1, W2, b2, W3, b3, flag, out);
}

// Round 4
// 226.556 us; speedup vs baseline: 2.8257x; 1.1225x over previous
//
#include <hip/hip_runtime.h>

#define N_NODES 100000
#define N_EDGES 600000
#define NT1 782    // node tiles of 128
#define NT2 4688   // edge tiles of 128
#define LDH 136    // padded row stride (bf16 elems), 16B-aligned rows
#define G1H 384    // k1 blocks per half (grid = 768)

typedef __attribute__((ext_vector_type(8))) short bf16x8;
typedef __attribute__((ext_vector_type(4))) float f32x4;

__device__ __forceinline__ float elu_f(float v) {
    return v > 0.0f ? v : (__expf(v) - 1.0f);
}

__device__ __forceinline__ unsigned short bf_rne(float f) {
    unsigned u = __float_as_uint(f);
    return (unsigned short)((u + 0x7fffu + ((u >> 16) & 1u)) >> 16);
}

__device__ __forceinline__ float bf2f(unsigned short h) {
    return __uint_as_float(((unsigned)h) << 16);
}

__device__ __forceinline__ void split2(float f, unsigned short& h, unsigned short& l) {
    h = bf_rne(f);
    l = bf_rne(f - bf2f(h));
}

// Detect whether edge_index arrived as int64 (odd 32-bit words all zero) or int32.
extern "C" __global__ void k_detect(const unsigned* __restrict__ ei, int* __restrict__ flag) {
    int t = threadIdx.x;  // 64 threads
    unsigned v = ei[2 * t + 1];
    unsigned long long b = __ballot(v == 0u);
    if (t == 0) *flag = (b == ~0ull) ? 1 : 0;
}

// P[n][half*128 + j] = bf16( x[n] @ W1[half*128 + k][j] )  — P stored bf16 (51.2 MB).
// A = RNE(x) single bf16; B = W1 split hi+lo (exact to ~2^-17). Coalesced bf16 epilogue
// via LDS bounce (reuses sX).
extern "C" __global__ __launch_bounds__(256, 3)
void k1_node_linear(const float* __restrict__ x, const float* __restrict__ W1,
                    unsigned short* __restrict__ P) {
    __shared__ __align__(16) unsigned short sX[128 * LDH];

    const int t = threadIdx.x;
    const int w = t >> 6, lane = t & 63;
    const int ln = lane & 15, kg = lane >> 4;
    const int kcf = t & 15;   // fixed k-chunk per thread for staging
    const int lef = t >> 4;   // row-group base for staging
    const int half = (blockIdx.x >= G1H) ? 1 : 0;
    const int t0 = blockIdx.x - half * G1H;

    // W1 fragments (hi+lo) for this wave's 32-col strip, cached in registers.
    bf16x8 bhi[2][4], blo[2][4];
#pragma unroll
    for (int c = 0; c < 2; ++c) {
        const int n = w * 32 + c * 16 + ln;
#pragma unroll
        for (int ks = 0; ks < 4; ++ks) {
            bf16x8 vh, vl;
#pragma unroll
            for (int j = 0; j < 8; ++j) {
                int k = half * 128 + ks * 32 + kg * 8 + j;
                unsigned short h, l;
                split2(W1[k * 128 + n], h, l);
                vh[j] = (short)h; vl[j] = (short)l;
            }
            bhi[c][ks] = vh; blo[c][ks] = vl;
        }
    }

    for (int tile = t0; tile < NT1; tile += G1H) {
        const int n0 = tile * 128;
        __syncthreads();   // previous iteration's epilogue reads done
#pragma unroll 2
        for (int r = 0; r < 8; ++r) {
            int le = r * 16 + lef;
            int n = n0 + le;
            float4 a0 = make_float4(0.f, 0.f, 0.f, 0.f), a1 = a0;
            if (n < N_NODES) {
                const float* p = x + (size_t)n * 128 + kcf * 8;
                a0 = *(const float4*)p; a1 = *(const float4*)(p + 4);
            }
            float f[8] = {a0.x, a0.y, a0.z, a0.w, a1.x, a1.y, a1.z, a1.w};
            bf16x8 vh;
#pragma unroll
            for (int j = 0; j < 8; ++j) vh[j] = (short)bf_rne(f[j]);
            *(bf16x8*)(&sX[le * LDH + kcf * 8]) = vh;
        }
        __syncthreads();

        f32x4 acc[8][2];
#pragma unroll
        for (int rt = 0; rt < 8; ++rt)
#pragma unroll
            for (int c = 0; c < 2; ++c) acc[rt][c] = (f32x4){0.f, 0.f, 0.f, 0.f};

#pragma unroll
        for (int ks = 0; ks < 4; ++ks) {
#pragma unroll
            for (int rt = 0; rt < 8; ++rt) {
                bf16x8 a = *(const bf16x8*)(&sX[(rt * 16 + ln) * LDH + ks * 32 + kg * 8]);
#pragma unroll
                for (int c = 0; c < 2; ++c) {
                    acc[rt][c] = __builtin_amdgcn_mfma_f32_16x16x32_bf16(a, bhi[c][ks], acc[rt][c], 0, 0, 0);
                    acc[rt][c] = __builtin_amdgcn_mfma_f32_16x16x32_bf16(a, blo[c][ks], acc[rt][c], 0, 0, 0);
                }
            }
        }

        // Epilogue: C-layout (col=lane&15, row=(lane>>4)*4+reg) -> LDS bounce -> coalesced
        // bf16 stores. Two 64-row chunks reusing sX.
#pragma unroll
        for (int ch = 0; ch < 2; ++ch) {
            __syncthreads();   // MFMA reads of sX (ch=0) / chunk reads (ch=1) done
#pragma unroll
            for (int rt2 = 0; rt2 < 4; ++rt2) {
                int rt = ch * 4 + rt2;
#pragma unroll
                for (int c = 0; c < 2; ++c) {
                    int col = w * 32 + c * 16 + ln;
#pragma unroll
                    for (int reg = 0; reg < 4; ++reg) {
                        int row = rt2 * 16 + kg * 4 + reg;
                        sX[row * LDH + col] = bf_rne(acc[rt][c][reg]);
                    }
                }
            }
            __syncthreads();
            int row_l = t >> 2, cg = t & 3;
            int n = n0 + ch * 64 + row_l;
            if (n < N_NODES) {
                unsigned short* dst = P + (size_t)n * 256 + half * 128 + cg * 32;
                const unsigned short* srcp = &sX[row_l * LDH + cg * 32];
#pragma unroll
                for (int i = 0; i < 4; ++i)
                    *(bf16x8*)(dst + i * 8) = *(const bf16x8*)(srcp + i * 8);
            }
        }
    }
}

// Per 128-edge tile: h1=elu(A[src]+B[tgt]+b1); h2=elu(h1@W2+b2); out=h2@W3+b3.
// P is bf16; A = RNE(h1) single bf16 in LDS; B = W2 split hi+lo in registers.
extern "C" __global__ __launch_bounds__(256, 3)
void k2_edge_mlp(const unsigned short* __restrict__ P, const void* __restrict__ eiv,
                 const float* __restrict__ b1, const float* __restrict__ W2,
                 const float* __restrict__ b2, const float* __restrict__ W3,
                 const float* __restrict__ b3, const int* __restrict__ flag,
                 float* __restrict__ out) {
    __shared__ __align__(16) unsigned short sH[128 * LDH];
    __shared__ float sPart[4 * 128];
    __shared__ int sSrc[128], sTgt[128];

    const int t = threadIdx.x;
    const int w = t >> 6, lane = t & 63;
    const int ln = lane & 15, kg = lane >> 4;
    const int kcf = t & 15;
    const int lef = t >> 4;
    const int mode64 = *flag;
    const float b3v = b3[0];

    // Loop-invariant register caches.
    float b1v[8];
#pragma unroll
    for (int j = 0; j < 8; ++j) b1v[j] = b1[kcf * 8 + j];
    float w3v[2], b2v[2];
#pragma unroll
    for (int c = 0; c < 2; ++c) {
        int col = w * 32 + c * 16 + ln;
        w3v[c] = W3[col]; b2v[c] = b2[col];
    }

    // W2 fragments (hi+lo) for this wave's 32-col strip.
    bf16x8 bhi[2][4], blo[2][4];
#pragma unroll
    for (int c = 0; c < 2; ++c) {
        const int n = w * 32 + c * 16 + ln;
#pragma unroll
        for (int ks = 0; ks < 4; ++ks) {
            bf16x8 vh, vl;
#pragma unroll
            for (int j = 0; j < 8; ++j) {
                int k = ks * 32 + kg * 8 + j;
                unsigned short h, l;
                split2(W2[k * 128 + n], h, l);
                vh[j] = (short)h; vl[j] = (short)l;
            }
            bhi[c][ks] = vh; blo[c][ks] = vl;
        }
    }

    for (int tile = blockIdx.x; tile < NT2; tile += gridDim.x) {
        const int e0 = tile * 128;
        __syncthreads();  // protect sSrc/sH/sPart from previous iteration
        if (t < 128) {
            int e = e0 + t;
            int s = 0, g = 0;
            if (e < N_EDGES) {
                if (mode64) {
                    s = (int)((const long long*)eiv)[e];
                    g = (int)((const long long*)eiv)[N_EDGES + e];
                } else {
                    s = ((const int*)eiv)[e];
                    g = ((const int*)eiv)[N_EDGES + e];
                }
            }
            sSrc[t] = s; sTgt[t] = g;
        }
        __syncthreads();

        // Gather (bf16) + bias + elu + RNE bf16.
#pragma unroll 2
        for (int r = 0; r < 8; ++r) {
            int le = r * 16 + lef;
            int s = sSrc[le], g = sTgt[le];
            bf16x8 a8 = *(const bf16x8*)(P + (size_t)s * 256 + kcf * 8);
            bf16x8 c8 = *(const bf16x8*)(P + (size_t)g * 256 + 128 + kcf * 8);
            bf16x8 vh;
#pragma unroll
            for (int j = 0; j < 8; ++j) {
                float hv = elu_f(bf2f((unsigned short)a8[j]) + bf2f((unsigned short)c8[j]) + b1v[j]);
                vh[j] = (short)bf_rne(hv);
            }
            *(bf16x8*)(&sH[le * LDH + kcf * 8]) = vh;
        }
        __syncthreads();

        f32x4 acc[8][2];
#pragma unroll
        for (int rt = 0; rt < 8; ++rt)
#pragma unroll
            for (int c = 0; c < 2; ++c) acc[rt][c] = (f32x4){0.f, 0.f, 0.f, 0.f};

#pragma unroll
        for (int ks = 0; ks < 4; ++ks) {
#pragma unroll
            for (int rt = 0; rt < 8; ++rt) {
                bf16x8 a = *(const bf16x8*)(&sH[(rt * 16 + ln) * LDH + ks * 32 + kg * 8]);
#pragma unroll
                for (int c = 0; c < 2; ++c) {
                    acc[rt][c] = __builtin_amdgcn_mfma_f32_16x16x32_bf16(a, bhi[c][ks], acc[rt][c], 0, 0, 0);
                    acc[rt][c] = __builtin_amdgcn_mfma_f32_16x16x32_bf16(a, blo[c][ks], acc[rt][c], 0, 0, 0);
                }
            }
        }

        // Layer 3 fused: per-lane partial dot over its 2 cols, 16-lane shuffle reduce.
#pragma unroll
        for (int rt = 0; rt < 8; ++rt) {
            float p[4] = {0.f, 0.f, 0.f, 0.f};
#pragma unroll
            for (int c = 0; c < 2; ++c) {
#pragma unroll
                for (int reg = 0; reg < 4; ++reg)
                    p[reg] += elu_f(acc[rt][c][reg] + b2v[c]) * w3v[c];
            }
#pragma unroll
            for (int m = 1; m < 16; m <<= 1)
#pragma unroll
                for (int reg = 0; reg < 4; ++reg) p[reg] += __shfl_xor(p[reg], m, 64);
            if (ln == 0) {
#pragma unroll
                for (int reg = 0; reg < 4; ++reg)
                    sPart[w * 128 + rt * 16 + kg * 4 + reg] = p[reg];
            }
        }
        __syncthreads();
        if (t < 128) {
            int e = e0 + t;
            if (e < N_EDGES)
                out[e] = sPart[t] + sPart[128 + t] + sPart[256 + t] + sPart[384 + t] + b3v;
        }
    }
}

extern "C" void kernel_launch(void* const* d_in, const int* in_sizes, int n_in,
                              void* d_out, int out_size, void* d_ws, size_t ws_size,
                              hipStream_t stream) {
    const float* x  = (const float*)d_in[0];
    const void*  ei = d_in[1];
    const float* W1 = (const float*)d_in[2];
    const float* b1 = (const float*)d_in[3];
    const float* W2 = (const float*)d_in[4];
    const float* b2 = (const float*)d_in[5];
    const float* W3 = (const float*)d_in[6];
    const float* b3 = (const float*)d_in[7];
    float* out = (float*)d_out;

    int* flag = (int*)d_ws;
    unsigned short* P = (unsigned short*)((char*)d_ws + 256);  // 100000*256 bf16 = 51.2 MB

    k_detect<<<1, 64, 0, stream>>>((const unsigned*)ei, flag);
    k1_node_linear<<<768, 256, 0, stream>>>(x, W1, P);
    k2_edge_mlp<<<768, 256, 0, stream>>>(P, ei, b1, W2, b2, W3, b3, flag, out);
}

// Round 5
// 222.018 us; speedup vs baseline: 2.8834x; 1.0204x over previous
//
#include <hip/hip_runtime.h>

#define N_NODES 100000
#define N_EDGES 600000
#define NT1 782    // node tiles of 128
#define NT2 4688   // edge tiles of 128
#define LDH 136    // padded row stride (f16 elems), 16B-aligned rows, 2-way-conflict free
#define G1H 512    // k1 blocks per half (grid = 1024)

typedef _Float16 f16x8 __attribute__((ext_vector_type(8)));
typedef __attribute__((ext_vector_type(4))) float f32x4;

__device__ __forceinline__ float elu_f(float v) {
    return v > 0.0f ? v : (__expf(v) - 1.0f);
}

// Detect whether edge_index arrived as int64 (odd 32-bit words all zero) or int32.
extern "C" __global__ void k_detect(const unsigned* __restrict__ ei, int* __restrict__ flag) {
    int t = threadIdx.x;  // 64 threads
    unsigned v = ei[2 * t + 1];
    unsigned long long b = __ballot(v == 0u);
    if (t == 0) *flag = (b == ~0ull) ? 1 : 0;
}

// P[n][half*128 + j] = f16( x[n] @ W1[half*128 + k][j] ).  Single-pass f16 MFMA:
// A = RNE-f16(x), B = RNE-f16(W1) (both 2^-11 rel). Coalesced f16 epilogue via full
// 128-row LDS bounce (reuses sX).
extern "C" __global__ __launch_bounds__(256, 4)
void k1_node_linear(const float* __restrict__ x, const float* __restrict__ W1,
                    _Float16* __restrict__ P) {
    __shared__ __align__(16) _Float16 sX[128 * LDH];

    const int t = threadIdx.x;
    const int w = t >> 6, lane = t & 63;
    const int ln = lane & 15, kg = lane >> 4;
    const int kcf = t & 15;   // fixed k-chunk per thread for staging
    const int lef = t >> 4;   // row-group base for staging
    const int half = (blockIdx.x >= G1H) ? 1 : 0;
    const int t0 = blockIdx.x - half * G1H;

    // W1 fragments (single f16) for this wave's 32-col strip, cached in registers.
    f16x8 bf[2][4];
#pragma unroll
    for (int c = 0; c < 2; ++c) {
        const int n = w * 32 + c * 16 + ln;
#pragma unroll
        for (int ks = 0; ks < 4; ++ks) {
            f16x8 v;
#pragma unroll
            for (int j = 0; j < 8; ++j) {
                int k = half * 128 + ks * 32 + kg * 8 + j;
                v[j] = (_Float16)W1[k * 128 + n];
            }
            bf[c][ks] = v;
        }
    }

    for (int tile = t0; tile < NT1; tile += G1H) {
        const int n0 = tile * 128;
        __syncthreads();   // T: previous epilogue's sX reads done
#pragma unroll 2
        for (int r = 0; r < 8; ++r) {
            int le = r * 16 + lef;
            int n = n0 + le;
            float4 a0 = make_float4(0.f, 0.f, 0.f, 0.f), a1 = a0;
            if (n < N_NODES) {
                const float* p = x + (size_t)n * 128 + kcf * 8;
                a0 = *(const float4*)p; a1 = *(const float4*)(p + 4);
            }
            float f[8] = {a0.x, a0.y, a0.z, a0.w, a1.x, a1.y, a1.z, a1.w};
            f16x8 vh;
#pragma unroll
            for (int j = 0; j < 8; ++j) vh[j] = (_Float16)f[j];
            *(f16x8*)(&sX[le * LDH + kcf * 8]) = vh;
        }
        __syncthreads();   // A: sX ready

        f32x4 acc[8][2];
#pragma unroll
        for (int rt = 0; rt < 8; ++rt)
#pragma unroll
            for (int c = 0; c < 2; ++c) acc[rt][c] = (f32x4){0.f, 0.f, 0.f, 0.f};

#pragma unroll
        for (int ks = 0; ks < 4; ++ks) {
#pragma unroll
            for (int rt = 0; rt < 8; ++rt) {
                f16x8 a = *(const f16x8*)(&sX[(rt * 16 + ln) * LDH + ks * 32 + kg * 8]);
#pragma unroll
                for (int c = 0; c < 2; ++c)
                    acc[rt][c] = __builtin_amdgcn_mfma_f32_16x16x32_f16(a, bf[c][ks], acc[rt][c], 0, 0, 0);
            }
        }

        __syncthreads();   // B: MFMA reads of sX done; reuse as epilogue bounce
        // C-layout: col=lane&15, row=(lane>>4)*4+reg  [measured m89/m91]
#pragma unroll
        for (int rt = 0; rt < 8; ++rt)
#pragma unroll
            for (int c = 0; c < 2; ++c) {
                int col = w * 32 + c * 16 + ln;
#pragma unroll
                for (int reg = 0; reg < 4; ++reg) {
                    int row = rt * 16 + kg * 4 + reg;
                    sX[row * LDH + col] = (_Float16)acc[rt][c][reg];
                }
            }
        __syncthreads();   // C: bounce ready
        {
            int row_l = t >> 1, seg = t & 1;
            int n = n0 + row_l;
            if (n < N_NODES) {
                _Float16* dst = P + (size_t)n * 256 + half * 128 + seg * 64;
                const _Float16* srcp = &sX[row_l * LDH + seg * 64];
#pragma unroll
                for (int i = 0; i < 8; ++i)
                    *(f16x8*)(dst + i * 8) = *(const f16x8*)(srcp + i * 8);
            }
        }
    }
}

// Per 128-edge tile: h1=elu(A[src]+B[tgt]+b1); h2=elu(h1@W2+b2); out=h2@W3+b3.
// P is f16; A = RNE-f16(h1) in LDS; B = RNE-f16(W2) in registers (single pass).
// 3 barriers/tile: out-write merged with next-tile index prefetch.
extern "C" __global__ __launch_bounds__(256, 4)
void k2_edge_mlp(const _Float16* __restrict__ P, const void* __restrict__ eiv,
                 const float* __restrict__ b1, const float* __restrict__ W2,
                 const float* __restrict__ b2, const float* __restrict__ W3,
                 const float* __restrict__ b3, const int* __restrict__ flag,
                 float* __restrict__ out) {
    __shared__ __align__(16) _Float16 sH[128 * LDH];
    __shared__ float sPart[4 * 128];
    __shared__ int sSrc[128], sTgt[128];

    const int t = threadIdx.x;
    const int w = t >> 6, lane = t & 63;
    const int ln = lane & 15, kg = lane >> 4;
    const int kcf = t & 15;
    const int lef = t >> 4;
    const int mode64 = *flag;
    const float b3v = b3[0];

    // Loop-invariant register caches.
    float b1v[8];
#pragma unroll
    for (int j = 0; j < 8; ++j) b1v[j] = b1[kcf * 8 + j];
    float w3v[2], b2v[2];
#pragma unroll
    for (int c = 0; c < 2; ++c) {
        int col = w * 32 + c * 16 + ln;
        w3v[c] = W3[col]; b2v[c] = b2[col];
    }

    // W2 fragments (single f16) for this wave's 32-col strip.
    f16x8 bf[2][4];
#pragma unroll
    for (int c = 0; c < 2; ++c) {
        const int n = w * 32 + c * 16 + ln;
#pragma unroll
        for (int ks = 0; ks < 4; ++ks) {
            f16x8 v;
#pragma unroll
            for (int j = 0; j < 8; ++j) {
                int k = ks * 32 + kg * 8 + j;
                v[j] = (_Float16)W2[k * 128 + n];
            }
            bf[c][ks] = v;
        }
    }

    // Prime indices for the first tile.
    int tile = blockIdx.x;
    if (t < 128 && tile < NT2) {
        int e = tile * 128 + t;
        int s = 0, g = 0;
        if (e < N_EDGES) {
            if (mode64) {
                s = (int)((const long long*)eiv)[e];
                g = (int)((const long long*)eiv)[N_EDGES + e];
            } else {
                s = ((const int*)eiv)[e];
                g = ((const int*)eiv)[N_EDGES + e];
            }
        }
        sSrc[t] = s; sTgt[t] = g;
    }
    __syncthreads();

    for (; tile < NT2; tile += gridDim.x) {
        const int e0 = tile * 128;

        // Gather (f16) + bias + elu + RNE-f16.
#pragma unroll 2
        for (int r = 0; r < 8; ++r) {
            int le = r * 16 + lef;
            int s = sSrc[le], g = sTgt[le];
            f16x8 a8 = *(const f16x8*)(P + (size_t)s * 256 + kcf * 8);
            f16x8 c8 = *(const f16x8*)(P + (size_t)g * 256 + 128 + kcf * 8);
            f16x8 vh;
#pragma unroll
            for (int j = 0; j < 8; ++j) {
                float hv = elu_f((float)a8[j] + (float)c8[j] + b1v[j]);
                vh[j] = (_Float16)hv;
            }
            *(f16x8*)(&sH[le * LDH + kcf * 8]) = vh;
        }
        __syncthreads();   // A: sH ready (also: prev sPart reads done)

        f32x4 acc[8][2];
#pragma unroll
        for (int rt = 0; rt < 8; ++rt)
#pragma unroll
            for (int c = 0; c < 2; ++c) acc[rt][c] = (f32x4){0.f, 0.f, 0.f, 0.f};

#pragma unroll
        for (int ks = 0; ks < 4; ++ks) {
#pragma unroll
            for (int rt = 0; rt < 8; ++rt) {
                f16x8 a = *(const f16x8*)(&sH[(rt * 16 + ln) * LDH + ks * 32 + kg * 8]);
#pragma unroll
                for (int c = 0; c < 2; ++c)
                    acc[rt][c] = __builtin_amdgcn_mfma_f32_16x16x32_f16(a, bf[c][ks], acc[rt][c], 0, 0, 0);
            }
        }

        // Layer 3 fused: per-lane partial dot over its 2 cols, 16-lane shuffle reduce.
#pragma unroll
        for (int rt = 0; rt < 8; ++rt) {
            float p[4] = {0.f, 0.f, 0.f, 0.f};
#pragma unroll
            for (int c = 0; c < 2; ++c) {
#pragma unroll
                for (int reg = 0; reg < 4; ++reg)
                    p[reg] += elu_f(acc[rt][c][reg] + b2v[c]) * w3v[c];
            }
#pragma unroll
            for (int m = 1; m < 16; m <<= 1)
#pragma unroll
                for (int reg = 0; reg < 4; ++reg) p[reg] += __shfl_xor(p[reg], m, 64);
            if (ln == 0) {
#pragma unroll
                for (int reg = 0; reg < 4; ++reg)
                    sPart[w * 128 + rt * 16 + kg * 4 + reg] = p[reg];
            }
        }
        __syncthreads();   // B: sPart ready; sH MFMA reads done

        // Out-write for this tile + index prefetch for the next, one phase.
        if (t < 128) {
            int e = e0 + t;
            if (e < N_EDGES)
                out[e] = sPart[t] + sPart[128 + t] + sPart[256 + t] + sPart[384 + t] + b3v;
            int nt = tile + gridDim.x;
            if (nt < NT2) {
                int en = nt * 128 + t;
                int s = 0, g = 0;
                if (en < N_EDGES) {
                    if (mode64) {
                        s = (int)((const long long*)eiv)[en];
                        g = (int)((const long long*)eiv)[N_EDGES + en];
                    } else {
                        s = ((const int*)eiv)[en];
                        g = ((const int*)eiv)[N_EDGES + en];
                    }
                }
                sSrc[t] = s; sTgt[t] = g;
            }
        }
        __syncthreads();   // C: sSrc ready; sPart reads done
    }
}

extern "C" void kernel_launch(void* const* d_in, const int* in_sizes, int n_in,
                              void* d_out, int out_size, void* d_ws, size_t ws_size,
                              hipStream_t stream) {
    const float* x  = (const float*)d_in[0];
    const void*  ei = d_in[1];
    const float* W1 = (const float*)d_in[2];
    const float* b1 = (const float*)d_in[3];
    const float* W2 = (const float*)d_in[4];
    const float* b2 = (const float*)d_in[5];
    const float* W3 = (const float*)d_in[6];
    const float* b3 = (const float*)d_in[7];
    float* out = (float*)d_out;

    int* flag = (int*)d_ws;
    _Float16* P = (_Float16*)((char*)d_ws + 256);  // 100000*256 f16 = 51.2 MB

    k_detect<<<1, 64, 0, stream>>>((const unsigned*)ei, flag);
    k1_node_linear<<<1024, 256, 0, stream>>>(x, W1, P);
    k2_edge_mlp<<<1024, 256, 0, stream>>>(P, ei, b1, W2, b2, W3, b3, flag, out);
}